// Round 7
// baseline (3423.089 us; speedup 1.0000x reference)
//
#include <hip/hip_runtime.h>

typedef short bf16x8 __attribute__((ext_vector_type(8)));
typedef float f32x4 __attribute__((ext_vector_type(4)));
typedef unsigned int u32;
typedef unsigned short u16;

#define B_ 128
#define T_ 256
#define E_ 256
#define H_ 256

#define AL(p) __hip_atomic_load((p), __ATOMIC_RELAXED, __HIP_MEMORY_SCOPE_AGENT)
#define AS(p,v) __hip_atomic_store((p), (v), __ATOMIC_RELAXED, __HIP_MEMORY_SCOPE_AGENT)

__device__ __forceinline__ u16 f2bf(float f){
  u32 x = __float_as_uint(f);
  x += 0x7FFFu + ((x >> 16) & 1u);   // RNE
  return (u16)(x >> 16);
}
__device__ __forceinline__ float bf2f(u16 v){ return __uint_as_float(((u32)v) << 16); }
__device__ __forceinline__ float sigf(float x){ return 1.0f/(1.0f + __expf(-x)); }
__device__ __forceinline__ float tanhf_(float x){ return 2.0f/(1.0f + __expf(-2.0f*x)) - 1.0f; }

// ---------------- f32 -> bf16 convert ----------------
__global__ void cvt4(const float* __restrict__ s, u16* __restrict__ d, int n4){
  int i = blockIdx.x*blockDim.x + threadIdx.x;
  int st = gridDim.x*blockDim.x;
  for (; i < n4; i += st){
    float4 f = ((const float4*)s)[i];
    ushort4 o;
    o.x=f2bf(f.x); o.y=f2bf(f.y); o.z=f2bf(f.z); o.w=f2bf(f.w);
    ((ushort4*)d)[i] = o;
  }
}

// ---------------- phase 1a: leaf buffers ----------------
__global__ __launch_bounds__(256) void leaf_kernel(
    const u16* __restrict__ xb, const u16* __restrict__ wxb, const u16* __restrict__ wgb,
    const float* __restrict__ bx, const float* __restrict__ bg,
    float* __restrict__ c_buf, u16* __restrict__ h_buf){
  int wid  = (blockIdx.x << 2) | (threadIdx.x >> 6);
  int lane = threadIdx.x & 63;
  int mt = wid >> 4, nt = wid & 15;
  int m0 = mt << 4, h0 = nt << 4;
  int lr = lane & 15, lg = lane >> 4;
  f32x4 accC = {0,0,0,0}, accG = {0,0,0,0};
  int arow = (m0 + lr) * E_;
  int wrow = (h0 + lr) * E_;
  #pragma unroll
  for (int c = 0; c < 8; ++c){
    int kb = c*32 + lg*8;
    bf16x8 af = *(const bf16x8*)(xb  + arow + kb);
    bf16x8 wx = *(const bf16x8*)(wxb + wrow + kb);
    bf16x8 wg = *(const bf16x8*)(wgb + wrow + kb);
    accC = __builtin_amdgcn_mfma_f32_16x16x32_bf16(af, wx, accC, 0,0,0);
    accG = __builtin_amdgcn_mfma_f32_16x16x32_bf16(af, wg, accG, 0,0,0);
  }
  int h = h0 + lr;
  float bxv = bx[h], bgv = bg[h];
  #pragma unroll
  for (int q = 0; q < 4; ++q){
    int m = m0 + lg*4 + q;
    float cv = accC[q] + bxv;
    float hv = sigf(accG[q] + bgv) * tanhf_(cv);
    c_buf[m*H_ + h] = cv;
    h_buf[m*H_ + h] = f2bf(hv);
  }
}

// ---------------- phase 1b: projL (leaf half of proj, incl. bias) ----------
__global__ __launch_bounds__(256) void projl2_kernel(
    const u16* __restrict__ wrb, const float* __restrict__ br,
    const u16* __restrict__ h_buf, u16* __restrict__ projL){
  int wv = threadIdx.x >> 6, lane = threadIdx.x & 63;
  int lr = lane & 15, lg = lane >> 4;
  int id = blockIdx.x*4 + wv;           // 0..639
  int bt = id & 7, gj = id >> 3;        // gj = g*16 + j16
  int g = gj >> 4, j16 = gj & 15;
  bf16x8 af[8];
  {
    const u16* wp = wrb + (u32)(g*256 + j16*16 + lr)*512 + 256 + lg*8;
    #pragma unroll
    for (int c = 0; c < 8; ++c) af[c] = *(const bf16x8*)(wp + c*32);
  }
  float bias[4];
  #pragma unroll
  for (int q = 0; q < 4; ++q) bias[q] = br[g*256 + j16*16 + lg*4 + q];
  const u16* hb = h_buf + ((u32)(bt*16 + lr)*T_)*H_ + lg*8;

  for (int i = 0; i < 128; ++i){
    int r0 = i, r1 = i + 128;
    bool ok1 = (r1 < 255);
    int t0 = 254 - r0, t1 = 254 - r1;
    bf16x8 b0[8], b1[8];
    #pragma unroll
    for (int c = 0; c < 8; ++c) b0[c] = *(const bf16x8*)(hb + t0*H_ + c*32);
    if (ok1){
      #pragma unroll
      for (int c = 0; c < 8; ++c) b1[c] = *(const bf16x8*)(hb + t1*H_ + c*32);
    }
    f32x4 a0, a1;
    #pragma unroll
    for (int q = 0; q < 4; ++q){ a0[q] = bias[q]; a1[q] = bias[q]; }
    #pragma unroll
    for (int c = 0; c < 8; ++c){
      a0 = __builtin_amdgcn_mfma_f32_16x16x32_bf16(af[c], b0[c], a0, 0,0,0);
      if (ok1) a1 = __builtin_amdgcn_mfma_f32_16x16x32_bf16(af[c], b1[c], a1, 0,0,0);
    }
    #pragma unroll
    for (int q = 0; q < 4; ++q){
      u32 grow = (u32)(g*256 + j16*16 + lg*4 + q);
      projL[(((u32)r0*8 + bt)*1280 + grow)*16 + lr] = f2bf(a0[q]);
      if (ok1) projL[(((u32)r1*8 + bt)*1280 + grow)*16 + lr] = f2bf(a1[q]);
    }
  }
}

// ---------------- phase 2: pairwise recurrence + ablation variants ----------
// MODE 0: real kernel (255 steps, writes out).
// MODE 1: no-spin ablation (510 steps): full compute/memory path, cross-WG
//         wait removed -> measures the compute+memory floor.
// MODE 2: protocol-only ablation (510 steps): no MFMA/LDS/projL/c_buf;
//         identical tagged store->poll pattern -> measures handoff latency.
template<int MODE>
__global__ __launch_bounds__(512, 2) void tree3t(
    const u16* __restrict__ wrb, const float* __restrict__ c_buf,
    const u16* __restrict__ h_buf, const u16* __restrict__ projL,
    u32* __restrict__ h_tag, float* __restrict__ outp){
  __shared__ __align__(16) char Sst[8192];   // 16 b x 256 k bf16, XOR-swizzled
  const int tid = threadIdx.x;
  const int wv = tid >> 6, lane = tid & 63;
  const int lr = lane & 15, lg = lane >> 4;
  const int pr = blockIdx.x & 7, hf = blockIdx.x >> 3;
  const int b0 = pr << 4;
  const int jb = hf << 7, pjb = jb ^ 128;
  const int jg = jb + wv*16 + lr;
  const int cb = hf << 2;
  const int NT = (MODE == 0) ? 255 : 510;

  bf16x8 wf[5][8];
  if constexpr (MODE != 2){
    #pragma unroll
    for (int g = 0; g < 5; ++g){
      const u16* wp = wrb + (u32)(g*256 + jg)*512 + lg*8;
      #pragma unroll
      for (int c = 0; c < 4; ++c){
        wf[g][c]   = *(const bf16x8*)(wp + (cb + c)*32);
        wf[g][4+c] = *(const bf16x8*)(wp + ((cb ^ 4) + c)*32);
      }
    }
  }

  float cst[4];
  #pragma unroll
  for (int q = 0; q < 4; ++q)
    cst[q] = c_buf[((b0 + lg*4 + q)*T_ + 255)*H_ + jg];

  if constexpr (MODE != 2){
    int bl = tid >> 5, cq = tid & 31;
    bf16x8 v = *(const bf16x8*)(h_buf + ((b0+bl)*T_ + 255)*H_ + cq*8);
    *(bf16x8*)&Sst[((bl<<9) + (cq<<4)) ^ ((bl&7)<<4)] = v;
  }
  ushort4 pf[5];
  if constexpr (MODE != 2){
    #pragma unroll
    for (int g = 0; g < 5; ++g)
      pf[g] = *(const ushort4*)(projL + (((u32)0*8 + pr)*1280 + g*256 + jg)*16 + lg*4);
  }
  __syncthreads();

  const int blp = tid >> 5, jqp = tid & 31;

  for (int r = 0; r < NT; ++r){
    const int rr = r % 255;
    float clf[4];
    if constexpr (MODE != 2){
      #pragma unroll
      for (int q = 0; q < 4; ++q)
        clf[q] = c_buf[((b0 + lg*4 + q)*T_ + (254-rr))*H_ + jg];
    }

    u32 v0=0,v1=0,v2=0,v3=0;
    const u32* sp = h_tag + ((r-1)&1)*32768 + ((b0+blp)<<8) + pjb + (jqp<<2);
    if (r){ v0=AL(sp); v1=AL(sp+1); v2=AL(sp+2); v3=AL(sp+3); }

    f32x4 acc[5];
    if constexpr (MODE != 2){
      #pragma unroll
      for (int g = 0; g < 5; ++g){
        acc[g][0]=bf2f(pf[g].x); acc[g][1]=bf2f(pf[g].y);
        acc[g][2]=bf2f(pf[g].z); acc[g][3]=bf2f(pf[g].w);
      }
      #pragma unroll
      for (int c = 0; c < 4; ++c){
        int off = ((lr<<9) + ((cb+c)<<6) + (lg<<4)) ^ ((lr&7)<<4);
        bf16x8 a = *(const bf16x8*)&Sst[off];
        #pragma unroll
        for (int g = 0; g < 5; ++g)
          acc[g] = __builtin_amdgcn_mfma_f32_16x16x32_bf16(a, wf[g][c], acc[g], 0,0,0);
      }
    }

    if (r){
      if constexpr (MODE != 1){
        const u32 want = ((u32)r) << 16;
        while ((((v0^want)|(v1^want)|(v2^want)|(v3^want)) >> 16) != 0u){
          v0=AL(sp); v1=AL(sp+1); v2=AL(sp+2); v3=AL(sp+3);
        }
      }
    }

    if constexpr (MODE != 2){
      if (rr < 254){
        #pragma unroll
        for (int g = 0; g < 5; ++g)
          pf[g] = *(const ushort4*)(projL + (((u32)(rr+1)*8 + pr)*1280 + g*256 + jg)*16 + lg*4);
      }
      if (r){
        uint2 pk;
        pk.x = (v0 & 0xFFFFu) | (v1 << 16);
        pk.y = (v2 & 0xFFFFu) | (v3 << 16);
        *(uint2*)&Sst[((blp<<9) + ((pjb + (jqp<<2))<<1)) ^ ((blp&7)<<4)] = pk;
      }
    }
    __syncthreads();   // bar1

    if constexpr (MODE != 2){
      #pragma unroll
      for (int c = 0; c < 4; ++c){
        int cc = (cb ^ 4) + c;
        int off = ((lr<<9) + (cc<<6) + (lg<<4)) ^ ((lr&7)<<4);
        bf16x8 a = *(const bf16x8*)&Sst[off];
        #pragma unroll
        for (int g = 0; g < 5; ++g)
          acc[g] = __builtin_amdgcn_mfma_f32_16x16x32_bf16(a, wf[g][4+c], acc[g], 0,0,0);
      }
    }

    #pragma unroll
    for (int q = 0; q < 4; ++q){
      float hn;
      if constexpr (MODE == 2){
        // dependency on polled values keeps the cross-WG chain real
        float cn = cst[q]*0.5f + (float)((v0 ^ (v1>>1) ^ (v2>>2) ^ (v3>>3)) & 0xFFu)*1e-20f;
        hn = cn; cst[q] = cn;
      } else {
        float iv = acc[0][q], fl = acc[1][q], fr = acc[2][q];
        float gv = acc[3][q], ov = acc[4][q];
        float cn = sigf(fl)*cst[q] + sigf(fr)*clf[q] + sigf(iv)*tanhf_(gv);
        hn = sigf(ov)*tanhf_(cn);
        cst[q] = cn;
      }
      if (r < NT-1){
        AS(h_tag + (r&1)*32768 + ((b0+lg*4+q)<<8) + jg,
           (((u32)(r+1)) << 16) | (u32)f2bf(hn));
        if constexpr (MODE != 2)
          *(u16*)&Sst[(((lg*4+q)<<9) + (jg<<1)) ^ (((lg*4+q)&7)<<4)] = f2bf(hn);
      } else {
        outp[(b0+lg*4+q)*H_ + jg] = hn;
      }
    }
    __syncthreads();   // bar2
  }
}

// ---------------- launch ----------------
extern "C" void kernel_launch(void* const* d_in, const int* in_sizes, int n_in,
                              void* d_out, int out_size, void* d_ws, size_t ws_size,
                              hipStream_t stream){
  const float* x  = (const float*)d_in[0];
  const float* Wx = (const float*)d_in[2];
  const float* bx = (const float*)d_in[3];
  const float* Wg = (const float*)d_in[4];
  const float* bg = (const float*)d_in[5];
  const float* Wr = (const float*)d_in[6];
  const float* br = (const float*)d_in[7];
  float* out = (float*)d_out;

  char* ws = (char*)d_ws;
  u16*   xb    = (u16*)(ws);                  // 16,777,216 B (dead after leaf)
  u16*   wxb   = (u16*)(ws + 16777216);
  u16*   wgb   = (u16*)(ws + 16908288);
  u16*   h_buf = (u16*)(ws + 17039360);
  float* c_buf = (float*)(ws + 33816576);
  u32*   h_tag = (u32*)(ws + 67371008);
  u16*   wrb   = (u16*)(ws + 67633152);
  u16*   projL = (u16*)(ws + 68943872);       // -> end 152,502,272

  // ablation scratch inside the dead xb region
  u32*   tagA = (u32*)(ws);                   // 262,144 B
  u32*   tagB = (u32*)(ws + 262144);          // 262,144 B
  float* outA = (float*)(ws + 524288);        // 131,072 B
  float* outB = (float*)(ws + 655360);        // 131,072 B

  cvt4<<<2048, 256, 0, stream>>>(x,  xb,  8388608/4);
  cvt4<<<64,   256, 0, stream>>>(Wx, wxb, 65536/4);
  cvt4<<<64,   256, 0, stream>>>(Wg, wgb, 65536/4);
  cvt4<<<640,  256, 0, stream>>>(Wr, wrb, 655360/4);
  leaf_kernel<<<8192, 256, 0, stream>>>(xb, wxb, wgb, bx, bg, c_buf, h_buf);
  hipMemsetAsync(h_tag, 0, 262144, stream);
  projl2_kernel<<<160, 256, 0, stream>>>(wrb, br, h_buf, projL);
  tree3t<0><<<16, 512, 0, stream>>>(wrb, c_buf, h_buf, projL, h_tag, out);

  // ---- diagnostics (results unused; timings read from rocprof table) ----
  hipMemsetAsync(tagA, 0, 262144, stream);
  tree3t<1><<<16, 512, 0, stream>>>(wrb, c_buf, h_buf, projL, tagA, outA);
  hipMemsetAsync(tagB, 0, 262144, stream);
  tree3t<2><<<16, 512, 0, stream>>>(wrb, c_buf, h_buf, projL, tagB, outB);
}

// Round 10
// 1586.679 us; speedup vs baseline: 2.1574x; 2.1574x over previous
//
#include <hip/hip_runtime.h>

typedef short bf16x8 __attribute__((ext_vector_type(8)));
typedef float f32x4 __attribute__((ext_vector_type(4)));
typedef unsigned int u32;
typedef unsigned short u16;

#define B_ 128
#define T_ 256
#define E_ 256
#define H_ 256

#define AL(p) __hip_atomic_load((p), __ATOMIC_RELAXED, __HIP_MEMORY_SCOPE_AGENT)
#define AS(p,v) __hip_atomic_store((p), (v), __ATOMIC_RELAXED, __HIP_MEMORY_SCOPE_AGENT)

__device__ __forceinline__ u16 f2bf(float f){
  u32 x = __float_as_uint(f);
  x += 0x7FFFu + ((x >> 16) & 1u);   // RNE
  return (u16)(x >> 16);
}
__device__ __forceinline__ float bf2f(u16 v){ return __uint_as_float(((u32)v) << 16); }
__device__ __forceinline__ float sigf(float x){ return 1.0f/(1.0f + __expf(-x)); }
__device__ __forceinline__ float tanhf_(float x){ return 2.0f/(1.0f + __expf(-2.0f*x)) - 1.0f; }

// ---------------- f32 -> bf16 convert ----------------
__global__ void cvt4(const float* __restrict__ s, u16* __restrict__ d, int n4){
  int i = blockIdx.x*blockDim.x + threadIdx.x;
  int st = gridDim.x*blockDim.x;
  for (; i < n4; i += st){
    float4 f = ((const float4*)s)[i];
    ushort4 o;
    o.x=f2bf(f.x); o.y=f2bf(f.y); o.z=f2bf(f.z); o.w=f2bf(f.w);
    ((ushort4*)d)[i] = o;
  }
}

// ---------------- phase 1a: leaf buffers ----------------
__global__ __launch_bounds__(256) void leaf_kernel(
    const u16* __restrict__ xb, const u16* __restrict__ wxb, const u16* __restrict__ wgb,
    const float* __restrict__ bx, const float* __restrict__ bg,
    float* __restrict__ c_buf, u16* __restrict__ h_buf){
  int wid  = (blockIdx.x << 2) | (threadIdx.x >> 6);
  int lane = threadIdx.x & 63;
  int mt = wid >> 4, nt = wid & 15;
  int m0 = mt << 4, h0 = nt << 4;
  int lr = lane & 15, lg = lane >> 4;
  f32x4 accC = {0,0,0,0}, accG = {0,0,0,0};
  int arow = (m0 + lr) * E_;
  int wrow = (h0 + lr) * E_;
  #pragma unroll
  for (int c = 0; c < 8; ++c){
    int kb = c*32 + lg*8;
    bf16x8 af = *(const bf16x8*)(xb  + arow + kb);
    bf16x8 wx = *(const bf16x8*)(wxb + wrow + kb);
    bf16x8 wg = *(const bf16x8*)(wgb + wrow + kb);
    accC = __builtin_amdgcn_mfma_f32_16x16x32_bf16(af, wx, accC, 0,0,0);
    accG = __builtin_amdgcn_mfma_f32_16x16x32_bf16(af, wg, accG, 0,0,0);
  }
  int h = h0 + lr;
  float bxv = bx[h], bgv = bg[h];
  #pragma unroll
  for (int q = 0; q < 4; ++q){
    int m = m0 + lg*4 + q;
    float cv = accC[q] + bxv;
    float hv = sigf(accG[q] + bgv) * tanhf_(cv);
    c_buf[m*H_ + h] = cv;
    h_buf[m*H_ + h] = f2bf(hv);
  }
}

// ---------------- phase 1b: projL (leaf half of proj, incl. bias) ----------
// projL[r][pr][g][bl 0..15][j 0..255] (j contiguous) — lane owns 4
// consecutive j for one batch: 8 B vector store here, 8 B load in tree4.
__global__ __launch_bounds__(256) void projl2_kernel(
    const u16* __restrict__ wrb, const float* __restrict__ br,
    const u16* __restrict__ h_buf, u16* __restrict__ projL){
  int wv = threadIdx.x >> 6, lane = threadIdx.x & 63;
  int lr = lane & 15, lg = lane >> 4;
  int id = blockIdx.x*4 + wv;           // 0..639
  int bt = id & 7, gj = id >> 3;        // gj = g*16 + j16
  int g = gj >> 4, j16 = gj & 15;
  bf16x8 af[8];
  {
    const u16* wp = wrb + (u32)(g*256 + j16*16 + lr)*512 + 256 + lg*8;
    #pragma unroll
    for (int c = 0; c < 8; ++c) af[c] = *(const bf16x8*)(wp + c*32);
  }
  float bias[4];
  #pragma unroll
  for (int q = 0; q < 4; ++q) bias[q] = br[g*256 + j16*16 + lg*4 + q];
  const u16* hb = h_buf + ((u32)(bt*16 + lr)*T_)*H_ + lg*8;

  for (int i = 0; i < 128; ++i){
    int r0 = i, r1 = i + 128;
    bool ok1 = (r1 < 255);
    int t0 = 254 - r0, t1 = 254 - r1;
    bf16x8 b0[8], b1[8];
    #pragma unroll
    for (int c = 0; c < 8; ++c) b0[c] = *(const bf16x8*)(hb + t0*H_ + c*32);
    if (ok1){
      #pragma unroll
      for (int c = 0; c < 8; ++c) b1[c] = *(const bf16x8*)(hb + t1*H_ + c*32);
    }
    f32x4 a0, a1;
    #pragma unroll
    for (int q = 0; q < 4; ++q){ a0[q] = bias[q]; a1[q] = bias[q]; }
    #pragma unroll
    for (int c = 0; c < 8; ++c){
      a0 = __builtin_amdgcn_mfma_f32_16x16x32_bf16(af[c], b0[c], a0, 0,0,0);
      if (ok1) a1 = __builtin_amdgcn_mfma_f32_16x16x32_bf16(af[c], b1[c], a1, 0,0,0);
    }
    // lane owns j = j16*16 + lg*4 + 0..3 (D rows), batch = bt*16 + lr (D col)
    ushort4 o0, o1;
    o0.x=f2bf(a0[0]); o0.y=f2bf(a0[1]); o0.z=f2bf(a0[2]); o0.w=f2bf(a0[3]);
    u32 base0 = ((((u32)r0*8 + bt)*5 + g)*16 + lr)*256 + j16*16 + lg*4;
    *(ushort4*)(projL + base0) = o0;
    if (ok1){
      o1.x=f2bf(a1[0]); o1.y=f2bf(a1[1]); o1.z=f2bf(a1[2]); o1.w=f2bf(a1[3]);
      u32 base1 = ((((u32)r1*8 + bt)*5 + g)*16 + lr)*256 + j16*16 + lg*4;
      *(ushort4*)(projL + base1) = o1;
    }
  }
}

// ---------------- phase 2: pairwise recurrence, transposed orientation ------
// 16 WGs = 8 pairs x 2 j-halves; 8 waves. mfma(A=W, B=h): D row = j, col = b.
// Lane owns batch b0+lr and 4 CONSECUTIVE j -> c_leaf = one float4 load,
// own-LDS h = one 8 B write, out = one float4 store.
// Tag store: 4x __hip_atomic_store AGENT (R9 lesson: hand-rolled
// global_store_dwordx4 sc0 sc1 never became visible to the partner XCD's
// agent-scope polls -> deadlock. Use the proven intrinsic.)
// Spin watchdog: bounded reload count turns any residual deadlock into a
// finite failed bench with counters instead of a 600 s timeout.
__global__ __launch_bounds__(512, 2) void tree4_kernel(
    const u16* __restrict__ wrb, const float* __restrict__ c_buf,
    const u16* __restrict__ h_buf, const u16* __restrict__ projL,
    u32* __restrict__ h_tag, float* __restrict__ out){
  __shared__ __align__(16) char Sst[8192];   // h_state: 16 b x 256 j bf16, XOR-swizzled
  const int tid = threadIdx.x;
  const int wv = tid >> 6, lane = tid & 63;
  const int lr = lane & 15, lg = lane >> 4;
  const int pr = blockIdx.x & 7, hf = blockIdx.x >> 3;  // partners co-XCD (perf only)
  const int b0 = pr << 4;
  const int jb = hf << 7, pjb = jb ^ 128;
  const int jw = jb + wv*16;                 // wave's 16-j block (weight rows)
  const int jcol = jw + lg*4;                // lane's 4-j base
  const int bL = b0 + lr;                    // lane's batch
  const int cb = hf << 2;                    // own k-frag base

  // resident weights as A-operand: rows g*256 + jw + lr; [0..3] own k-half,
  // [4..7] partner half (literal indices only — R4 lesson)
  bf16x8 wf[5][8];
  #pragma unroll
  for (int g = 0; g < 5; ++g){
    const u16* wp = wrb + (u32)(g*256 + jw + lr)*512 + lg*8;
    #pragma unroll
    for (int c = 0; c < 4; ++c){
      wf[g][c]   = *(const bf16x8*)(wp + (cb + c)*32);
      wf[g][4+c] = *(const bf16x8*)(wp + ((cb ^ 4) + c)*32);
    }
  }

  // initial cell state: c(leaf 255) for (bL, jcol..jcol+3)
  float cst[4];
  {
    float4 cs = *(const float4*)(c_buf + (bL*T_ + 255)*H_ + jcol);
    cst[0]=cs.x; cst[1]=cs.y; cst[2]=cs.z; cst[3]=cs.w;
  }

  // prologue: stage FULL h(leaf255) tile; prefetch projL r=0
  {
    int bl = tid >> 5, cq = tid & 31;
    bf16x8 v = *(const bf16x8*)(h_buf + ((b0+bl)*T_ + 255)*H_ + cq*8);
    *(bf16x8*)&Sst[((bl<<9) + (cq<<4)) ^ ((bl&7)<<4)] = v;
  }
  ushort4 pf[5];
  #pragma unroll
  for (int g = 0; g < 5; ++g)
    pf[g] = *(const ushort4*)(projL + ((((u32)0*8 + pr)*5 + g)*16 + lr)*256 + jcol);
  __syncthreads();

  const int blp = tid >> 5, jqp = tid & 31;  // poll: row blp, partner j-quad jqp

  for (int r = 0; r < 255; ++r){
    // c_leaf: one float4 (used at bottom -> full-step latency cover)
    float clf[4];
    {
      float4 cv = *(const float4*)(c_buf + (bL*T_ + (254-r))*H_ + jcol);
      clf[0]=cv.x; clf[1]=cv.y; clf[2]=cv.z; clf[3]=cv.w;
    }

    // issue partner poll loads early
    u32 v0=0,v1=0,v2=0,v3=0;
    const u32* sp = h_tag + ((r-1)&1)*32768 + ((b0+blp)<<8) + pjb + (jqp<<2);
    if (r){ v0=AL(sp); v1=AL(sp+1); v2=AL(sp+2); v3=AL(sp+3); }

    // acc init from projL (prefetched)
    f32x4 acc[5];
    #pragma unroll
    for (int g = 0; g < 5; ++g){
      acc[g][0]=bf2f(pf[g].x); acc[g][1]=bf2f(pf[g].y);
      acc[g][2]=bf2f(pf[g].z); acc[g][3]=bf2f(pf[g].w);
    }

    // own-k-half MFMAs (B-frag = Sst rows lr, own k-chunks)
    #pragma unroll
    for (int c = 0; c < 4; ++c){
      int off = ((lr<<9) + ((cb+c)<<6) + (lg<<4)) ^ ((lr&7)<<4);
      bf16x8 b = *(const bf16x8*)&Sst[off];
      #pragma unroll
      for (int g = 0; g < 5; ++g)
        acc[g] = __builtin_amdgcn_mfma_f32_16x16x32_bf16(wf[g][c], b, acc[g], 0,0,0);
    }

    // finish poll (watchdog-bounded)
    if (r){
      const u32 want = ((u32)r) << 16;
      int budget = 1 << 14;
      while ((((v0^want)|(v1^want)|(v2^want)|(v3^want)) >> 16) != 0u && --budget){
        v0=AL(sp); v1=AL(sp+1); v2=AL(sp+2); v3=AL(sp+3);
      }
    }

    // prefetch next projL (post-spin so spin retries don't drain it)
    if (r < 254){
      #pragma unroll
      for (int g = 0; g < 5; ++g)
        pf[g] = *(const ushort4*)(projL + ((((u32)(r+1)*8 + pr)*5 + g)*16 + lr)*256 + jcol);
    }

    // stage partner half (8 B per thread)
    if (r){
      uint2 pk;
      pk.x = (v0 & 0xFFFFu) | (v1 << 16);
      pk.y = (v2 & 0xFFFFu) | (v3 << 16);
      *(uint2*)&Sst[((blp<<9) + ((pjb + (jqp<<2))<<1)) ^ ((blp&7)<<4)] = pk;
    }
    __syncthreads();   // bar1: partner half staged; own-half reads done

    // partner-k-half MFMAs
    #pragma unroll
    for (int c = 0; c < 4; ++c){
      int cc = (cb ^ 4) + c;
      int off = ((lr<<9) + (cc<<6) + (lg<<4)) ^ ((lr&7)<<4);
      bf16x8 b = *(const bf16x8*)&Sst[off];
      #pragma unroll
      for (int g = 0; g < 5; ++g)
        acc[g] = __builtin_amdgcn_mfma_f32_16x16x32_bf16(wf[g][4+c], b, acc[g], 0,0,0);
    }

    // cell elementwise: lane owns (bL, jcol..jcol+3); c_state in-register
    float hn[4];
    #pragma unroll
    for (int q = 0; q < 4; ++q){
      float iv = acc[0][q], fl = acc[1][q], fr = acc[2][q];
      float gv = acc[3][q], ov = acc[4][q];
      float cn = sigf(fl)*cst[q] + sigf(fr)*clf[q] + sigf(iv)*tanhf_(gv);
      hn[q] = sigf(ov)*tanhf_(cn);
      cst[q] = cn;
    }
    if (r < 254){
      // tagged words for partner: 4 adjacent device-scope stores (proven path)
      const u32 tg = ((u32)(r+1)) << 16;
      u32* tp = h_tag + (r&1)*32768 + (bL<<8) + jcol;
      AS(tp,   tg | (u32)f2bf(hn[0]));
      AS(tp+1, tg | (u32)f2bf(hn[1]));
      AS(tp+2, tg | (u32)f2bf(hn[2]));
      AS(tp+3, tg | (u32)f2bf(hn[3]));
      // own LDS copy for next step (8 B)
      uint2 hw;
      hw.x = (u32)f2bf(hn[0]) | ((u32)f2bf(hn[1]) << 16);
      hw.y = (u32)f2bf(hn[2]) | ((u32)f2bf(hn[3]) << 16);
      *(uint2*)&Sst[((lr<<9) + (jcol<<1)) ^ ((lr&7)<<4)] = hw;
    } else {
      float4 o; o.x=hn[0]; o.y=hn[1]; o.z=hn[2]; o.w=hn[3];
      *(float4*)(out + bL*H_ + jcol) = o;
    }
    __syncthreads();   // bar2: partner-half reads done + own h_r visible
  }
}

// ---------------- launch ----------------
extern "C" void kernel_launch(void* const* d_in, const int* in_sizes, int n_in,
                              void* d_out, int out_size, void* d_ws, size_t ws_size,
                              hipStream_t stream){
  const float* x  = (const float*)d_in[0];
  const float* Wx = (const float*)d_in[2];
  const float* bx = (const float*)d_in[3];
  const float* Wg = (const float*)d_in[4];
  const float* bg = (const float*)d_in[5];
  const float* Wr = (const float*)d_in[6];
  const float* br = (const float*)d_in[7];
  float* out = (float*)d_out;

  char* ws = (char*)d_ws;
  u16*   xb    = (u16*)(ws);                  // 16,777,216 B
  u16*   wxb   = (u16*)(ws + 16777216);       //    131,072 B
  u16*   wgb   = (u16*)(ws + 16908288);       //    131,072 B
  u16*   h_buf = (u16*)(ws + 17039360);       // 16,777,216 B
  float* c_buf = (float*)(ws + 33816576);     // 33,554,432 B
  u32*   h_tag = (u32*)(ws + 67371008);       //    262,144 B
  u16*   wrb   = (u16*)(ws + 67633152);       //  1,310,720 B
  u16*   projL = (u16*)(ws + 68943872);       // 83,558,400 B -> end 152,502,272

  cvt4<<<2048, 256, 0, stream>>>(x,  xb,  8388608/4);
  cvt4<<<64,   256, 0, stream>>>(Wx, wxb, 65536/4);
  cvt4<<<64,   256, 0, stream>>>(Wg, wgb, 65536/4);
  cvt4<<<640,  256, 0, stream>>>(Wr, wrb, 655360/4);
  leaf_kernel<<<8192, 256, 0, stream>>>(xb, wxb, wgb, bx, bg, c_buf, h_buf);
  (void)hipMemsetAsync(h_tag, 0, 262144, stream);
  projl2_kernel<<<160, 256, 0, stream>>>(wrb, br, h_buf, projL);
  tree4_kernel<<<16, 512, 0, stream>>>(wrb, c_buf, h_buf, projL, h_tag, out);
}

// Round 11
// 1301.090 us; speedup vs baseline: 2.6309x; 1.2195x over previous
//
#include <hip/hip_runtime.h>

typedef short bf16x8 __attribute__((ext_vector_type(8)));
typedef float f32x4 __attribute__((ext_vector_type(4)));
typedef unsigned int u32;
typedef unsigned short u16;

#define B_ 128
#define T_ 256
#define E_ 256
#define H_ 256

#define AL(p) __hip_atomic_load((p), __ATOMIC_RELAXED, __HIP_MEMORY_SCOPE_AGENT)
#define AS(p,v) __hip_atomic_store((p), (v), __ATOMIC_RELAXED, __HIP_MEMORY_SCOPE_AGENT)

__device__ __forceinline__ u16 f2bf(float f){
  u32 x = __float_as_uint(f);
  x += 0x7FFFu + ((x >> 16) & 1u);   // RNE
  return (u16)(x >> 16);
}
__device__ __forceinline__ float bf2f(u16 v){ return __uint_as_float(((u32)v) << 16); }
__device__ __forceinline__ float sigf(float x){ return 1.0f/(1.0f + __expf(-x)); }
__device__ __forceinline__ float tanhf_(float x){ return 2.0f/(1.0f + __expf(-2.0f*x)) - 1.0f; }

// ---------------- f32 -> bf16 convert ----------------
__global__ void cvt4(const float* __restrict__ s, u16* __restrict__ d, int n4){
  int i = blockIdx.x*blockDim.x + threadIdx.x;
  int st = gridDim.x*blockDim.x;
  for (; i < n4; i += st){
    float4 f = ((const float4*)s)[i];
    ushort4 o;
    o.x=f2bf(f.x); o.y=f2bf(f.y); o.z=f2bf(f.z); o.w=f2bf(f.w);
    ((ushort4*)d)[i] = o;
  }
}

// ---------------- phase 1a: leaf buffers ----------------
__global__ __launch_bounds__(256) void leaf_kernel(
    const u16* __restrict__ xb, const u16* __restrict__ wxb, const u16* __restrict__ wgb,
    const float* __restrict__ bx, const float* __restrict__ bg,
    float* __restrict__ c_buf, u16* __restrict__ h_buf){
  int wid  = (blockIdx.x << 2) | (threadIdx.x >> 6);
  int lane = threadIdx.x & 63;
  int mt = wid >> 4, nt = wid & 15;
  int m0 = mt << 4, h0 = nt << 4;
  int lr = lane & 15, lg = lane >> 4;
  f32x4 accC = {0,0,0,0}, accG = {0,0,0,0};
  int arow = (m0 + lr) * E_;
  int wrow = (h0 + lr) * E_;
  #pragma unroll
  for (int c = 0; c < 8; ++c){
    int kb = c*32 + lg*8;
    bf16x8 af = *(const bf16x8*)(xb  + arow + kb);
    bf16x8 wx = *(const bf16x8*)(wxb + wrow + kb);
    bf16x8 wg = *(const bf16x8*)(wgb + wrow + kb);
    accC = __builtin_amdgcn_mfma_f32_16x16x32_bf16(af, wx, accC, 0,0,0);
    accG = __builtin_amdgcn_mfma_f32_16x16x32_bf16(af, wg, accG, 0,0,0);
  }
  int h = h0 + lr;
  float bxv = bx[h], bgv = bg[h];
  #pragma unroll
  for (int q = 0; q < 4; ++q){
    int m = m0 + lg*4 + q;
    float cv = accC[q] + bxv;
    float hv = sigf(accG[q] + bgv) * tanhf_(cv);
    c_buf[m*H_ + h] = cv;
    h_buf[m*H_ + h] = f2bf(hv);
  }
}

// ---------------- phase 1b: projL (leaf half of proj, incl. bias) ----------
// projL[r][bt][g][bl 0..15][j 0..255]. 640 blocks x 4 waves: wave owns
// (bt, g, j16) x one 64-r chunk -> ~10 waves/CU latency hiding (R10: old
// 160-block grid = 2.5 waves/CU, latency-exposed, ~250 us).
__global__ __launch_bounds__(256) void projl3_kernel(
    const u16* __restrict__ wrb, const float* __restrict__ br,
    const u16* __restrict__ h_buf, u16* __restrict__ projL){
  int wv = threadIdx.x >> 6, lane = threadIdx.x & 63;
  int lr = lane & 15, lg = lane >> 4;
  int id = blockIdx.x;                  // 0..639
  int bt = id & 7, gj = id >> 3;        // gj = g*16 + j16
  int g = gj >> 4, j16 = gj & 15;
  bf16x8 af[8];
  {
    const u16* wp = wrb + (u32)(g*256 + j16*16 + lr)*512 + 256 + lg*8;
    #pragma unroll
    for (int c = 0; c < 8; ++c) af[c] = *(const bf16x8*)(wp + c*32);
  }
  float bias[4];
  #pragma unroll
  for (int q = 0; q < 4; ++q) bias[q] = br[g*256 + j16*16 + lg*4 + q];
  const u16* hb = h_buf + ((u32)(bt*16 + lr)*T_)*H_ + lg*8;

  int rA = wv*64, rB = rA + 64; if (rB > 255) rB = 255;
  for (int r = rA; r < rB; ++r){
    int t = 254 - r;
    bf16x8 b[8];
    #pragma unroll
    for (int c = 0; c < 8; ++c) b[c] = *(const bf16x8*)(hb + t*H_ + c*32);
    f32x4 a;
    #pragma unroll
    for (int q = 0; q < 4; ++q) a[q] = bias[q];
    #pragma unroll
    for (int c = 0; c < 8; ++c)
      a = __builtin_amdgcn_mfma_f32_16x16x32_bf16(af[c], b[c], a, 0,0,0);
    ushort4 o;
    o.x=f2bf(a[0]); o.y=f2bf(a[1]); o.z=f2bf(a[2]); o.w=f2bf(a[3]);
    u32 base = ((((u32)r*8 + bt)*5 + g)*16 + lr)*256 + j16*16 + lg*4;
    *(ushort4*)(projL + base) = o;
  }
}

// ---------------- phase 2: pairwise recurrence ------------------------------
// 16 WGs = 8 pairs x 2 j-halves; 8 waves x 64. mfma(A=W, B=h): lane owns
// (batch b0+lr, 4 consecutive j). __launch_bounds__(512,1): R10 lesson —
// (512,2) forced 16 waves/CU -> 128-VGPR hardware cap -> the 160-VGPR weight
// array could never be resident (the 3 us/step "compute floor" of R7 was
// 640 KB/step of L2 weight re-fetch). 8 waves/CU -> 256-VGPR budget.
// Tag store: cooperative coalesced (R10: per-lane strided atomics caused 4x
// write amplification, WRITE_SIZE 130 MB). At top of step r, 512 threads
// read h_{r-1} from own-LDS transposed (thread owns words u+q*32) so each
// atomic store instruction covers contiguous 64-lane spans.
__global__ __launch_bounds__(512, 1) void tree4_kernel(
    const u16* __restrict__ wrb, const float* __restrict__ c_buf,
    const u16* __restrict__ h_buf, const u16* __restrict__ projL,
    u32* __restrict__ h_tag, float* __restrict__ out){
  __shared__ __align__(16) char Sst[8192];   // h_state: 16 b x 256 j bf16, XOR-swizzled
  const int tid = threadIdx.x;
  const int wv = tid >> 6, lane = tid & 63;
  const int lr = lane & 15, lg = lane >> 4;
  const int pr = blockIdx.x & 7, hf = blockIdx.x >> 3;  // partners co-XCD (perf only)
  const int b0 = pr << 4;
  const int jb = hf << 7, pjb = jb ^ 128;
  const int jw = jb + wv*16;                 // wave's 16-j block (weight rows)
  const int jcol = jw + lg*4;                // lane's 4-j base
  const int bL = b0 + lr;                    // lane's batch
  const int cb = hf << 2;                    // own k-frag base

  // resident weights: rows g*256 + jw + lr; [0..3] own k-half, [4..7] partner
  bf16x8 wf[5][8];
  #pragma unroll
  for (int g = 0; g < 5; ++g){
    const u16* wp = wrb + (u32)(g*256 + jw + lr)*512 + lg*8;
    #pragma unroll
    for (int c = 0; c < 4; ++c){
      wf[g][c]   = *(const bf16x8*)(wp + (cb + c)*32);
      wf[g][4+c] = *(const bf16x8*)(wp + ((cb ^ 4) + c)*32);
    }
  }

  // initial cell state: c(leaf 255) for (bL, jcol..jcol+3)
  float cst[4];
  {
    float4 cs = *(const float4*)(c_buf + (bL*T_ + 255)*H_ + jcol);
    cst[0]=cs.x; cst[1]=cs.y; cst[2]=cs.z; cst[3]=cs.w;
  }

  // prologue: stage FULL h(leaf255) tile; prefetch projL r=0
  {
    int bl = tid >> 5, cq = tid & 31;
    bf16x8 v = *(const bf16x8*)(h_buf + ((b0+bl)*T_ + 255)*H_ + cq*8);
    *(bf16x8*)&Sst[((bl<<9) + (cq<<4)) ^ ((bl&7)<<4)] = v;
  }
  ushort4 pf[5];
  #pragma unroll
  for (int g = 0; g < 5; ++g)
    pf[g] = *(const ushort4*)(projL + ((((u32)0*8 + pr)*5 + g)*16 + lr)*256 + jcol);
  __syncthreads();

  const int blp = tid >> 5, jqp = tid & 31;  // poll: row blp, partner j-quad jqp
  const int trow = tid >> 5, tu = tid & 31;  // coop tag store identity

  for (int r = 0; r < 255; ++r){
    // ---- cooperative coalesced tag store of h_{r-1} (tag value r) ----
    if (r){
      const u32 tg = ((u32)r) << 16;
      u32* tb = h_tag + ((r-1)&1)*32768 + ((b0+trow)<<8) + jb;
      #pragma unroll
      for (int q = 0; q < 4; ++q){
        int j2 = tu + q*32;                  // 0..127 within own half
        int jg2 = jb + j2;
        u16 hv = *(const u16*)&Sst[((trow<<9) + (jg2<<1)) ^ ((trow&7)<<4)];
        AS(tb + j2, tg | (u32)hv);
      }
    }

    // c_leaf: one float4 (used at bottom -> full-step latency cover)
    float clf[4];
    {
      float4 cv = *(const float4*)(c_buf + (bL*T_ + (254-r))*H_ + jcol);
      clf[0]=cv.x; clf[1]=cv.y; clf[2]=cv.z; clf[3]=cv.w;
    }

    // issue partner poll loads early
    u32 v0=0,v1=0,v2=0,v3=0;
    const u32* sp = h_tag + ((r-1)&1)*32768 + ((b0+blp)<<8) + pjb + (jqp<<2);
    if (r){ v0=AL(sp); v1=AL(sp+1); v2=AL(sp+2); v3=AL(sp+3); }

    // acc init from projL (prefetched)
    f32x4 acc[5];
    #pragma unroll
    for (int g = 0; g < 5; ++g){
      acc[g][0]=bf2f(pf[g].x); acc[g][1]=bf2f(pf[g].y);
      acc[g][2]=bf2f(pf[g].z); acc[g][3]=bf2f(pf[g].w);
    }

    // own-k-half MFMAs (overlap the poll)
    #pragma unroll
    for (int c = 0; c < 4; ++c){
      int off = ((lr<<9) + ((cb+c)<<6) + (lg<<4)) ^ ((lr&7)<<4);
      bf16x8 b = *(const bf16x8*)&Sst[off];
      #pragma unroll
      for (int g = 0; g < 5; ++g)
        acc[g] = __builtin_amdgcn_mfma_f32_16x16x32_bf16(wf[g][c], b, acc[g], 0,0,0);
    }

    // finish poll (watchdog-bounded: deadlock -> finite failed bench)
    if (r){
      const u32 want = ((u32)r) << 16;
      int budget = 1 << 14;
      while ((((v0^want)|(v1^want)|(v2^want)|(v3^want)) >> 16) != 0u && --budget){
        v0=AL(sp); v1=AL(sp+1); v2=AL(sp+2); v3=AL(sp+3);
      }
    }

    // prefetch next projL (post-spin so spin retries don't drain it)
    if (r < 254){
      #pragma unroll
      for (int g = 0; g < 5; ++g)
        pf[g] = *(const ushort4*)(projL + ((((u32)(r+1)*8 + pr)*5 + g)*16 + lr)*256 + jcol);
    }

    // stage partner half (8 B per thread)
    if (r){
      uint2 pk;
      pk.x = (v0 & 0xFFFFu) | (v1 << 16);
      pk.y = (v2 & 0xFFFFu) | (v3 << 16);
      *(uint2*)&Sst[((blp<<9) + ((pjb + (jqp<<2))<<1)) ^ ((blp&7)<<4)] = pk;
    }
    __syncthreads();   // bar1: partner half staged; own-half reads + coop reads done

    // partner-k-half MFMAs
    #pragma unroll
    for (int c = 0; c < 4; ++c){
      int cc = (cb ^ 4) + c;
      int off = ((lr<<9) + (cc<<6) + (lg<<4)) ^ ((lr&7)<<4);
      bf16x8 b = *(const bf16x8*)&Sst[off];
      #pragma unroll
      for (int g = 0; g < 5; ++g)
        acc[g] = __builtin_amdgcn_mfma_f32_16x16x32_bf16(wf[g][4+c], b, acc[g], 0,0,0);
    }

    // cell elementwise: lane owns (bL, jcol..jcol+3); c_state in-register
    float hn[4];
    #pragma unroll
    for (int q = 0; q < 4; ++q){
      float iv = acc[0][q], fl = acc[1][q], fr = acc[2][q];
      float gv = acc[3][q], ov = acc[4][q];
      float cn = sigf(fl)*cst[q] + sigf(fr)*clf[q] + sigf(iv)*tanhf_(gv);
      hn[q] = sigf(ov)*tanhf_(cn);
      cst[q] = cn;
    }
    if (r < 254){
      // own LDS copy (8 B) — next step's MFMA B-frags + coop tag store source
      uint2 hw;
      hw.x = (u32)f2bf(hn[0]) | ((u32)f2bf(hn[1]) << 16);
      hw.y = (u32)f2bf(hn[2]) | ((u32)f2bf(hn[3]) << 16);
      *(uint2*)&Sst[((lr<<9) + (jcol<<1)) ^ ((lr&7)<<4)] = hw;
    } else {
      float4 o; o.x=hn[0]; o.y=hn[1]; o.z=hn[2]; o.w=hn[3];
      *(float4*)(out + bL*H_ + jcol) = o;
    }
    __syncthreads();   // bar2: partner-half reads done + own h_r visible
  }
}

// ---------------- launch ----------------
extern "C" void kernel_launch(void* const* d_in, const int* in_sizes, int n_in,
                              void* d_out, int out_size, void* d_ws, size_t ws_size,
                              hipStream_t stream){
  const float* x  = (const float*)d_in[0];
  const float* Wx = (const float*)d_in[2];
  const float* bx = (const float*)d_in[3];
  const float* Wg = (const float*)d_in[4];
  const float* bg = (const float*)d_in[5];
  const float* Wr = (const float*)d_in[6];
  const float* br = (const float*)d_in[7];
  float* out = (float*)d_out;

  char* ws = (char*)d_ws;
  u16*   xb    = (u16*)(ws);                  // 16,777,216 B
  u16*   wxb   = (u16*)(ws + 16777216);       //    131,072 B
  u16*   wgb   = (u16*)(ws + 16908288);       //    131,072 B
  u16*   h_buf = (u16*)(ws + 17039360);       // 16,777,216 B
  float* c_buf = (float*)(ws + 33816576);     // 33,554,432 B
  u32*   h_tag = (u32*)(ws + 67371008);       //    262,144 B
  u16*   wrb   = (u16*)(ws + 67633152);       //  1,310,720 B
  u16*   projL = (u16*)(ws + 68943872);       // 83,558,400 B -> end 152,502,272

  cvt4<<<2048, 256, 0, stream>>>(x,  xb,  8388608/4);
  cvt4<<<64,   256, 0, stream>>>(Wx, wxb, 65536/4);
  cvt4<<<64,   256, 0, stream>>>(Wg, wgb, 65536/4);
  cvt4<<<640,  256, 0, stream>>>(Wr, wrb, 655360/4);
  leaf_kernel<<<8192, 256, 0, stream>>>(xb, wxb, wgb, bx, bg, c_buf, h_buf);
  (void)hipMemsetAsync(h_tag, 0, 262144, stream);
  projl3_kernel<<<640, 256, 0, stream>>>(wrb, br, h_buf, projL);
  tree4_kernel<<<16, 512, 0, stream>>>(wrb, c_buf, h_buf, projL, h_tag, out);
}